// Round 1
// 438.642 us; speedup vs baseline: 1.0142x; 1.0142x over previous
//
#include <hip/hip_runtime.h>
#include <hip/hip_bf16.h>
#include <math.h>

// ---------------------------------------------------------------------------
// Swin/SAM-style block. R9: replace libm erff in the fc1 gelu epilogue with a
// branchless A&S 7.1.26 erf (rcp + exp + 5-term poly, err 1.5e-7). The fc1
// mgemm was VALU-bound on the epilogue (VALUBusy 35% vs MfmaUtil 17.5%).
// ---------------------------------------------------------------------------

#define DIMC 768
#define HEADS 12
#define WIN 14
#define NTOK 196
#define NWIN 50
#define MROWS 9800
#define YROWS 8192
#define MLP_HID 3072

using bf16x8 = __attribute__((ext_vector_type(8))) short;
using f32x4  = __attribute__((ext_vector_type(4))) float;

__device__ __forceinline__ float bf2f(unsigned short u) {
    return __uint_as_float(((unsigned)u) << 16);
}
__device__ __forceinline__ unsigned short f2bf(float f) {
    unsigned u = __float_as_uint(f);
    unsigned r = (u + 0x7fffu + ((u >> 16) & 1u)) >> 16;   // round-nearest-even
    return (unsigned short)r;
}
__device__ __forceinline__ void gl2lds16(const unsigned short* g, unsigned short* l) {
    __builtin_amdgcn_global_load_lds(
        (const __attribute__((address_space(1))) void*)g,
        (__attribute__((address_space(3))) void*)l, 16, 0, 0);
}

// Branchless exact-enough gelu: 0.5*v*(1+erf(v/sqrt(2))).
// erf via Abramowitz-Stegun 7.1.26 (max err 1.5e-7 < bf16 quantum).
__device__ __forceinline__ float fast_gelu(float v) {
    float u = v * 0.70710678118654752f;
    float a = fabsf(u);
    float t = __builtin_amdgcn_rcpf(fmaf(0.3275911f, a, 1.0f));
    float p = t * fmaf(t, fmaf(t, fmaf(t, fmaf(t, 1.061405429f, -1.453152027f),
                       1.421413741f), -0.284496736f), 0.254829592f);
    float e = __expf(-u * u);
    float er = fmaf(-p, e, 1.0f);            // erf(|u|)
    er = copysignf(er, v);
    return 0.5f * v * (1.0f + er);
}

// ---------------- fused 4-way weight transpose: W (K x N, f32) -> Wt (N x K, bf16)
// block ranges: [0,432) qkv  [432,576) proj  [576,1152) fc1  [1152,1728) fc2
__global__ __launch_bounds__(256) void transpose_all(
        const float* __restrict__ Wq, unsigned short* __restrict__ Tq,
        const float* __restrict__ Wp, unsigned short* __restrict__ Tp,
        const float* __restrict__ W1, unsigned short* __restrict__ T1,
        const float* __restrict__ W2, unsigned short* __restrict__ T2) {
    int id = blockIdx.x;
    const float* W; unsigned short* Wt; int K, N, nbx, rel;
    if (id < 432)       { W = Wq; Wt = Tq; K = 768;  N = 2304; nbx = 36; rel = id; }
    else if (id < 576)  { W = Wp; Wt = Tp; K = 768;  N = 768;  nbx = 12; rel = id - 432; }
    else if (id < 1152) { W = W1; Wt = T1; K = 768;  N = 3072; nbx = 48; rel = id - 576; }
    else                { W = W2; Wt = T2; K = 3072; N = 768;  nbx = 12; rel = id - 1152; }
    int bx = rel % nbx, by = rel / nbx;
    __shared__ float t[64][65];
    int k0 = by << 6, n0 = bx << 6;
    int tn = threadIdx.x & 63;
    int tk = threadIdx.x >> 6;
    #pragma unroll
    for (int r = 0; r < 16; r++) {
        int k = tk + r * 4;
        t[k][tn] = W[(size_t)(k0 + k) * N + n0 + tn];
    }
    __syncthreads();
    #pragma unroll
    for (int r = 0; r < 16; r++) {
        int n = tk + r * 4;
        Wt[(size_t)(n0 + n) * K + k0 + tn] = f2bf(t[tn][n]);
    }
}

// ---------------- LN1 + window partition (zeros in padding) ----------------
__global__ __launch_bounds__(256) void ln1_win_kernel(
        const float* __restrict__ x, const float* __restrict__ g,
        const float* __restrict__ b, unsigned short* __restrict__ h1) {
    int tid = threadIdx.x;
    int row = blockIdx.x * 4 + (tid >> 6);
    int lane = tid & 63;
    if (row >= MROWS) return;
    int w = row / NTOK, t = row % NTOK;
    int bi = w / 25, wr = w % 25;
    int gy = (wr / 5) * WIN + t / WIN;
    int gx = (wr % 5) * WIN + t % WIN;
    unsigned short* out = h1 + (size_t)row * DIMC;
    if (gy >= 64 || gx >= 64) {           // reference pads AFTER LN -> zeros
        #pragma unroll
        for (int j = 0; j < 12; j++) out[lane + 64 * j] = 0;
        return;
    }
    const float* xr = x + ((size_t)((bi * 64 + gy) * 64 + gx)) * DIMC;
    float v[12], s = 0.f;
    #pragma unroll
    for (int j = 0; j < 12; j++) { v[j] = xr[lane + 64 * j]; s += v[j]; }
    #pragma unroll
    for (int o = 32; o > 0; o >>= 1) s += __shfl_xor(s, o);
    float mean = s * (1.f / 768.f);
    float q = 0.f;
    #pragma unroll
    for (int j = 0; j < 12; j++) { float d = v[j] - mean; q += d * d; }
    #pragma unroll
    for (int o = 32; o > 0; o >>= 1) q += __shfl_xor(q, o);
    float inv = rsqrtf(q * (1.f / 768.f) + 1e-6f);
    #pragma unroll
    for (int j = 0; j < 12; j++) {
        int c = lane + 64 * j;
        out[c] = f2bf((v[j] - mean) * inv * g[c] + b[c]);
    }
}

// ---------------- LN2 ----------------
__global__ __launch_bounds__(256) void ln2_kernel(
        const float* __restrict__ y, const float* __restrict__ g,
        const float* __restrict__ b, unsigned short* __restrict__ h2) {
    int tid = threadIdx.x;
    int row = blockIdx.x * 4 + (tid >> 6);
    int lane = tid & 63;
    const float* xr = y + (size_t)row * DIMC;
    float v[12], s = 0.f;
    #pragma unroll
    for (int j = 0; j < 12; j++) { v[j] = xr[lane + 64 * j]; s += v[j]; }
    #pragma unroll
    for (int o = 32; o > 0; o >>= 1) s += __shfl_xor(s, o);
    float mean = s * (1.f / 768.f);
    float q = 0.f;
    #pragma unroll
    for (int j = 0; j < 12; j++) { float d = v[j] - mean; q += d * d; }
    #pragma unroll
    for (int o = 32; o > 0; o >>= 1) q += __shfl_xor(q, o);
    float inv = rsqrtf(q * (1.f / 768.f) + 1e-6f);
    unsigned short* out = h2 + (size_t)row * DIMC;
    #pragma unroll
    for (int j = 0; j < 12; j++) {
        int c = lane + 64 * j;
        out[c] = f2bf((v[j] - mean) * inv * g[c] + b[c]);
    }
}

// ---------------- build A_aug (q | relh | relw | 0) and Vt per (win,head) ----
// rel dots via MFMA: dots[i][r] = q[i] . RT[r], RT = [relph(27) | relpw(27)].
// relh[i][c] = dots[i][13 + i/14 - c]; relw[i][c] = dots[i][27 + 13 + i%14 - c].
__global__ __launch_bounds__(256) void build_aug(
        const unsigned short* __restrict__ qkvb,
        const float* __restrict__ relph, const float* __restrict__ relpw,
        unsigned short* __restrict__ Aaug, unsigned short* __restrict__ Vt) {
    __shared__ unsigned short qs[208 * 72];   // pitch 72: b128-aligned, 2-way banks
    __shared__ unsigned short rt[64 * 72];
    int tid = threadIdx.x;
    int bh = blockIdx.x, w = bh / HEADS, head = bh % HEADS;
    int lane = tid & 63, wave = tid >> 6;
    int l15 = lane & 15, q4 = lane >> 4, q8 = q4 * 8;
    size_t base = (size_t)w * NTOK * 2304 + head * 64;
    unsigned short* ab = Aaug + (size_t)bh * 256 * 96;

    // stage q -> qs, copy to ab cols 0..63
    for (int e = tid; e < 196 * 8; e += 256) {
        int t = e >> 3, s8 = (e & 7) * 8;
        bf16x8 qv = *(const bf16x8*)&qkvb[base + (size_t)t * 2304 + s8];
        *(bf16x8*)&qs[t * 72 + s8] = qv;
        *(bf16x8*)&ab[t * 96 + s8] = qv;
    }
    for (int e = tid; e < 12 * 8; e += 256) {  // zero qs rows 196..207
        bf16x8 z = {};
        *(bf16x8*)&qs[(196 + (e >> 3)) * 72 + (e & 7) * 8] = z;
    }
    // stage RT tables (f32 -> bf16), rows 54..63 zero
    for (int e = tid; e < 64 * 8; e += 256) {
        int r = e >> 3, s8 = (e & 7) * 8;
        bf16x8 ov = {};
        if (r < 54) {
            const float* src = (r < 27 ? relph + (size_t)r * 64
                                       : relpw + (size_t)(r - 27) * 64) + s8;
            #pragma unroll
            for (int jj = 0; jj < 8; jj++) ov[jj] = (short)f2bf(src[jj]);
        }
        *(bf16x8*)&rt[r * 72 + s8] = ov;
    }
    // zero ab rows 196..255 (all 96 cols) and cols 92..95
    for (int e = tid; e < 60 * 12; e += 256) {
        bf16x8 z = {};
        *(bf16x8*)&ab[(size_t)(196 + e / 12) * 96 + (e % 12) * 8] = z;
    }
    for (int e = tid; e < 196; e += 256) {
        ab[e * 96 + 92] = 0; ab[e * 96 + 93] = 0;
        ab[e * 96 + 94] = 0; ab[e * 96 + 95] = 0;
    }
    __syncthreads();

    // rel MFMA + scatter into ab cols 64..91
    #pragma unroll
    for (int t = 0; t < 4; t++) {
        int it = wave * 4 + t;
        if (it >= 13) break;                      // wave-uniform
        bf16x8 a0 = *(bf16x8*)&qs[(it * 16 + l15) * 72 + q8];
        bf16x8 a1 = *(bf16x8*)&qs[(it * 16 + l15) * 72 + 32 + q8];
        #pragma unroll
        for (int rt4 = 0; rt4 < 4; rt4++) {
            bf16x8 b0 = *(bf16x8*)&rt[(rt4 * 16 + l15) * 72 + q8];
            bf16x8 b1 = *(bf16x8*)&rt[(rt4 * 16 + l15) * 72 + 32 + q8];
            f32x4 d4 = {};
            d4 = __builtin_amdgcn_mfma_f32_16x16x32_bf16(a0, b0, d4, 0, 0, 0);
            d4 = __builtin_amdgcn_mfma_f32_16x16x32_bf16(a1, b1, d4, 0, 0, 0);
            int rcol = rt4 * 16 + l15;
            #pragma unroll
            for (int r = 0; r < 4; r++) {
                int i = it * 16 + q4 * 4 + r;
                if (i < 196 && rcol < 54) {
                    if (rcol < 27) {
                        int c = 13 + i / 14 - rcol;
                        if (c >= 0 && c < 14) ab[i * 96 + 64 + c] = f2bf(d4[r]);
                    } else {
                        int c = 13 + i % 14 - (rcol - 27);
                        if (c >= 0 && c < 14) ab[i * 96 + 78 + c] = f2bf(d4[r]);
                    }
                }
            }
        }
    }

    // Vt[d][224]: vector read V, scalar global scatter (L2 write-combines)
    unsigned short* vtb = Vt + (size_t)bh * 64 * 224;
    for (int e = tid; e < 196 * 8; e += 256) {
        int j = e >> 3, dg = (e & 7) * 8;
        bf16x8 vv = *(const bf16x8*)&qkvb[base + 1536 + (size_t)j * 2304 + dg];
        #pragma unroll
        for (int k = 0; k < 8; k++)
            vtb[(size_t)(dg + k) * 224 + j] = (unsigned short)vv[k];
    }
    for (int e = tid; e < 64 * 28; e += 256)     // zero cols 196..223
        vtb[(size_t)(e / 28) * 224 + 196 + (e % 28)] = 0;
}

// ---------------- fused MFMA attention: one block per (window,head) --------
__global__ __launch_bounds__(256) void attn_mfma(
        const unsigned short* __restrict__ qkvb,
        const unsigned short* __restrict__ Aaug,
        const unsigned short* __restrict__ Vt,
        unsigned short* __restrict__ out) {
    __shared__ unsigned short Kls[208 * 96];   // K_aug: [k*0.125 | oh(j/14) | oh(j%14) | 0]
    __shared__ unsigned short Pls[4][64 * 40]; // per-wave P strip, pitch 40
    int tid = threadIdx.x;
    int bh = blockIdx.x, w = bh / HEADS, head = bh % HEADS;
    int wave = tid >> 6, lane = tid & 63;
    int l15 = lane & 15, q4 = lane >> 4, q8 = q4 * 8;
    size_t kbase = (size_t)w * NTOK * 2304 + head * 64 + 768;
    // stage K*0.125 (exact: pow2) rows 0..195
    for (int e = tid; e < 196 * 8; e += 256) {
        int t = e >> 3, s8 = (e & 7) * 8;
        bf16x8 kv = *(const bf16x8*)&qkvb[kbase + (size_t)t * 2304 + s8];
        bf16x8 ko;
        #pragma unroll
        for (int jj = 0; jj < 8; jj++)
            ko[jj] = (short)f2bf(bf2f((unsigned short)kv[jj]) * 0.125f);
        *(bf16x8*)&Kls[t * 96 + s8] = ko;
    }
    bf16x8 z8 = {};
    for (int e = tid; e < 208 * 4; e += 256)   // zero cols 64..95
        *(bf16x8*)&Kls[(e >> 2) * 96 + 64 + (e & 3) * 8] = z8;
    for (int e = tid; e < 12 * 8; e += 256)    // zero rows 196..207 cols 0..63
        *(bf16x8*)&Kls[(196 + (e >> 3)) * 96 + (e & 7) * 8] = z8;
    __syncthreads();                           // zeros before one-hots (same dwords)
    for (int e = tid; e < 196; e += 256) {
        Kls[e * 96 + 64 + e / WIN] = 0x3F80;   // bf16(1.0)
        Kls[e * 96 + 78 + e % WIN] = 0x3F80;
    }
    // A-frags from global (held in regs across all j-tiles)
    bf16x8 af[4][3];
    const unsigned short* abse = Aaug + (size_t)bh * 256 * 96;
    #pragma unroll
    for (int it = 0; it < 4; it++)
        #pragma unroll
        for (int c = 0; c < 3; c++)
            af[it][c] = *(const bf16x8*)&abse[(size_t)(wave * 64 + it * 16 + l15) * 96 + c * 32 + q8];
    __syncthreads();                           // K_aug complete

    const unsigned short* vtb = Vt + (size_t)bh * 64 * 224;
    f32x4 o[4][4] = {};
    float lacc[4][4] = {{0.f}};
    bf16x8 bv[4];
    #pragma unroll
    for (int dt = 0; dt < 4; dt++)
        bv[dt] = *(const bf16x8*)&vtb[(dt * 16 + l15) * 224 + q8];

    for (int jp = 0; jp < 7; jp++) {
        f32x4 s[4][2] = {};
        #pragma unroll
        for (int half = 0; half < 2; half++) {
            int jt = jp * 2 + half;
            if (jt < 13) {
                #pragma unroll
                for (int c = 0; c < 3; c++) {
                    bf16x8 bk = *(bf16x8*)&Kls[(jt * 16 + l15) * 96 + c * 32 + q8];
                    #pragma unroll
                    for (int it = 0; it < 4; it++)
                        s[it][half] = __builtin_amdgcn_mfma_f32_16x16x32_bf16(
                            af[it][c], bk, s[it][half], 0, 0, 0);
                }
            }
        }
        __syncthreads();   // WAR: previous PV reads of Pls complete
        #pragma unroll
        for (int half = 0; half < 2; half++) {
            int jt = jp * 2 + half;
            bool valid = (jt < 13) && (jt * 16 + l15) < 196;
            #pragma unroll
            for (int it = 0; it < 4; it++)
                #pragma unroll
                for (int r = 0; r < 4; r++) {
                    float p = valid ? __expf(s[it][half][r]) : 0.f;
                    unsigned short pb = f2bf(p);
                    lacc[it][r] += bf2f(pb);
                    Pls[wave][(it * 16 + q4 * 4 + r) * 40 + half * 16 + l15] = pb;
                }
        }
        __syncthreads();   // RAW: P visible
        bf16x8 ap[4];
        #pragma unroll
        for (int it = 0; it < 4; it++)
            ap[it] = *(bf16x8*)&Pls[wave][(it * 16 + l15) * 40 + q8];
        bf16x8 bvn[4];
        if (jp < 6) {
            #pragma unroll
            for (int dt = 0; dt < 4; dt++)
                bvn[dt] = *(const bf16x8*)&vtb[(dt * 16 + l15) * 224 + (jp + 1) * 32 + q8];
        }
        #pragma unroll
        for (int dt = 0; dt < 4; dt++)
            #pragma unroll
            for (int it = 0; it < 4; it++)
                o[it][dt] = __builtin_amdgcn_mfma_f32_16x16x32_bf16(
                    ap[it], bv[dt], o[it][dt], 0, 0, 0);
        if (jp < 6) {
            #pragma unroll
            for (int dt = 0; dt < 4; dt++) bv[dt] = bvn[dt];
        }
    }
    // row sums across the 16 j-lanes of each quad
    #pragma unroll
    for (int it = 0; it < 4; it++)
        #pragma unroll
        for (int r = 0; r < 4; r++) {
            float v = lacc[it][r];
            v += __shfl_xor(v, 1); v += __shfl_xor(v, 2);
            v += __shfl_xor(v, 4); v += __shfl_xor(v, 8);
            lacc[it][r] = 1.f / v;
        }
    // store O (win, token, head, d)
    #pragma unroll
    for (int it = 0; it < 4; it++) {
        int i0 = wave * 64 + it * 16 + q4 * 4;
        #pragma unroll
        for (int r = 0; r < 4; r++) {
            if (i0 + r < 196) {
                size_t rowb = (size_t)(w * NTOK + i0 + r) * DIMC + head * 64;
                #pragma unroll
                for (int dt = 0; dt < 4; dt++)
                    out[rowb + dt * 16 + l15] = f2bf(o[it][dt][r] * lacc[it][r]);
            }
        }
    }
}

// ---------------- MFMA GEMM (ping-pong dbuf + XCD swizzle + XOR LDS): -------
// C = A(MxK bf16) @ Bt(NxK bf16)^T + bias.  BM=128, BN in {128,64}, BK=32.
// Per iter: sync (drain prev loads) -> issue next-tile loads into buf^1 ->
// compute from buf (loads fly during compute; next sync drains them).
// EPI 0: bf16 store   EPI 1: fast exact-erf gelu -> bf16
// EPI 2: window-unpartition + x residual (f32)   EPI 3: + resid (f32)
template <int EPI, int BN>
__global__ __launch_bounds__(256) void mgemm(
        const unsigned short* __restrict__ A, const unsigned short* __restrict__ Bt,
        const float* __restrict__ bias, void* __restrict__ Cout,
        const float* __restrict__ resid, int M, int Nn, int K,
        int nbx, int nby) {
    const int NI = BN / 32;                 // per-wave n-frags
    __shared__ unsigned short As[2][128 * 32];
    __shared__ unsigned short Bs[2][BN * 32];
    int tid = threadIdx.x;
    int lane = tid & 63, wave = tid >> 6;
    int l15 = lane & 15, q4 = lane >> 4;
    int xq8 = (q4 ^ ((l15 >> 1) & 3)) * 8;  // swizzled frag segment (shorts)
    // ---- XCD swizzle ----
    int id = blockIdx.x;
    int per = nbx * 8;
    int s = id / per;
    int rem = id - s * per;
    int rmax = nby - s * 8; if (rmax > 8) rmax = 8;
    int bx = rem / rmax;
    int r_ = rem - bx * rmax;
    int by = s * 8 + r_;
    int m0 = by << 7, n0 = bx * BN;
    int wm = (wave >> 1) * 64, wn = (wave & 1) * (BN / 2);
    // staging: lane i -> row i/4, swizzled global seg; LDS dst = base + lane*16
    int srow0 = wave * 32 + (lane >> 2);
    int srow1 = srow0 + 16;
    int sseg = ((lane & 3) ^ ((lane >> 3) & 3)) * 8;   // shorts
    int rmA0 = m0 + srow0; if (rmA0 >= M) rmA0 = M - 1;   // clamp: rows>=M never stored
    int rmA1 = m0 + srow1; if (rmA1 >= M) rmA1 = M - 1;
    const unsigned short* gA0 = A + (size_t)rmA0 * K + sseg;
    const unsigned short* gA1 = A + (size_t)rmA1 * K + sseg;
    int browB = (BN == 128) ? srow0 : (wave * 16 + (lane >> 2));
    const unsigned short* gB0 = Bt + (size_t)(n0 + browB) * K + sseg;
    const unsigned short* gB1 = Bt + (size_t)(n0 + srow1) * K + sseg;  // BN=128 only
    int lofsA = wave * 1024 + lane * 8;
    int lofsB = ((BN == 128) ? wave * 1024 : wave * 512) + lane * 8;
    f32x4 acc[4][NI] = {};
    // prologue: stage tile 0 into buf 0
    gl2lds16(gA0, &As[0][lofsA]);
    gl2lds16(gA1, &As[0][lofsA + 512]);
    gl2lds16(gB0, &Bs[0][lofsB]);
    if (BN == 128) gl2lds16(gB1, &Bs[0][lofsB + 512]);
    int cur = 0;
    for (int k0 = 0; k0 < K; k0 += 32) {
        __syncthreads();                     // drain loads for buf cur
        int kn = k0 + 32;
        if (kn < K) {                        // prefetch next tile into buf cur^1
            gl2lds16(gA0 + kn, &As[cur ^ 1][lofsA]);
            gl2lds16(gA1 + kn, &As[cur ^ 1][lofsA + 512]);
            gl2lds16(gB0 + kn, &Bs[cur ^ 1][lofsB]);
            if (BN == 128) gl2lds16(gB1 + kn, &Bs[cur ^ 1][lofsB + 512]);
        }
        bf16x8 bfr[NI];
        #pragma unroll
        for (int ni = 0; ni < NI; ni++)
            bfr[ni] = *(bf16x8*)&Bs[cur][(wn + ni * 16 + l15) * 32 + xq8];
        #pragma unroll
        for (int mi = 0; mi < 4; mi++) {
            bf16x8 afr = *(bf16x8*)&As[cur][(wm + mi * 16 + l15) * 32 + xq8];
            #pragma unroll
            for (int ni = 0; ni < NI; ni++)
                acc[mi][ni] = __builtin_amdgcn_mfma_f32_16x16x32_bf16(
                    afr, bfr[ni], acc[mi][ni], 0, 0, 0);
        }
        cur ^= 1;
    }
    int q4r = (lane >> 4) * 4;
    #pragma unroll
    for (int mi = 0; mi < 4; mi++) {
        #pragma unroll
        for (int r = 0; r < 4; r++) {
            int row = m0 + wm + mi * 16 + q4r + r;
            if (row >= M) continue;
            if (EPI == 2) {
                int w = row / NTOK, t = row % NTOK;
                int bi = w / 25, wr = w % 25;
                int gy = (wr / 5) * WIN + t / WIN;
                int gx = (wr % 5) * WIN + t % WIN;
                if (gy >= 64 || gx >= 64) continue;
                size_t orow = ((size_t)((bi * 64 + gy) * 64 + gx)) * DIMC;
                #pragma unroll
                for (int ni = 0; ni < NI; ni++) {
                    int col = n0 + wn + ni * 16 + l15;
                    float v = acc[mi][ni][r] + bias[col];
                    ((float*)Cout)[orow + col] = resid[orow + col] + v;
                }
            } else {
                #pragma unroll
                for (int ni = 0; ni < NI; ni++) {
                    int col = n0 + wn + ni * 16 + l15;
                    float v = acc[mi][ni][r] + bias[col];
                    if (EPI == 0) {
                        ((unsigned short*)Cout)[(size_t)row * Nn + col] = f2bf(v);
                    } else if (EPI == 1) {
                        v = fast_gelu(v);
                        ((unsigned short*)Cout)[(size_t)row * Nn + col] = f2bf(v);
                    } else {
                        ((float*)Cout)[(size_t)row * Nn + col] =
                            resid[(size_t)row * Nn + col] + v;
                    }
                }
            }
        }
    }
}

// ---------------------------------------------------------------------------
extern "C" void kernel_launch(void* const* d_in, const int* in_sizes, int n_in,
                              void* d_out, int out_size, void* d_ws, size_t ws_size,
                              hipStream_t stream) {
    const float* x      = (const float*)d_in[0];
    const float* ln1_g  = (const float*)d_in[1];
    const float* ln1_b  = (const float*)d_in[2];
    const float* qkv_w  = (const float*)d_in[3];
    const float* qkv_b  = (const float*)d_in[4];
    const float* proj_w = (const float*)d_in[5];
    const float* proj_b = (const float*)d_in[6];
    const float* rel_h  = (const float*)d_in[7];
    const float* rel_w  = (const float*)d_in[8];
    const float* ln2_g  = (const float*)d_in[9];
    const float* ln2_b  = (const float*)d_in[10];
    const float* fc1_w  = (const float*)d_in[11];
    const float* fc1_b  = (const float*)d_in[12];
    const float* fc2_w  = (const float*)d_in[13];
    const float* fc2_b  = (const float*)d_in[14];
    float* out = (float*)d_out;
    char* ws = (char*)d_ws;

    // Workspace regions (max 121,061,376 B), liveness-checked (same as R3-R8):
    unsigned short* wt_qkv  = (unsigned short*)(ws);
    unsigned short* wt_proj = (unsigned short*)(ws + 3538944);
    unsigned short* wt_fc1  = (unsigned short*)(ws + 4718592);
    unsigned short* wt_fc2  = (unsigned short*)(ws + 9437184);
    unsigned short* qkvb    = (unsigned short*)(ws + 14155776);
    float*          yb      = (float*)        (ws + 14155776);
    unsigned short* h2      = (unsigned short*)(ws + 39321600);
    unsigned short* h1      = (unsigned short*)(ws + 59314176);
    unsigned short* attn_o  = h1;
    unsigned short* zb      = h1;
    unsigned short* Aaug    = (unsigned short*)(ws + 74366976);
    unsigned short* Vt      = (unsigned short*)(ws + 103858176);

    transpose_all<<<1728, 256, 0, stream>>>(
        qkv_w, wt_qkv, proj_w, wt_proj, fc1_w, wt_fc1, fc2_w, wt_fc2);

    ln1_win_kernel<<<(MROWS + 3) / 4, 256, 0, stream>>>(x, ln1_g, ln1_b, h1);

    mgemm<0, 128><<<18 * 77, 256, 0, stream>>>(
        h1, wt_qkv, qkv_b, qkvb, nullptr, MROWS, 2304, DIMC, 18, 77);

    build_aug<<<NWIN * HEADS, 256, 0, stream>>>(qkvb, rel_h, rel_w, Aaug, Vt);

    attn_mfma<<<NWIN * HEADS, 256, 0, stream>>>(qkvb, Aaug, Vt, attn_o);

    mgemm<2, 64><<<12 * 77, 256, 0, stream>>>(
        attn_o, wt_proj, proj_b, yb, x, MROWS, DIMC, DIMC, 12, 77);

    ln2_kernel<<<YROWS / 4, 256, 0, stream>>>(yb, ln2_g, ln2_b, h2);

    mgemm<1, 128><<<24 * 64, 256, 0, stream>>>(
        h2, wt_fc1, fc1_b, zb, nullptr, YROWS, MLP_HID, DIMC, 24, 64);

    mgemm<3, 64><<<12 * 64, 256, 0, stream>>>(
        zb, wt_fc2, fc2_b, out, yb, YROWS, DIMC, MLP_HID, 12, 64);
}

// Round 2
// 428.744 us; speedup vs baseline: 1.0376x; 1.0231x over previous
//
#include <hip/hip_runtime.h>
#include <hip/hip_bf16.h>
#include <math.h>

// ---------------------------------------------------------------------------
// Swin/SAM-style block. R10: mgemm K-loop rebuilt as a 3-buffer, 2-tile-ahead
// pipeline with raw s_barrier + counted s_waitcnt vmcnt(N) (T4). The old
// __syncthreads ping-pong drained vmcnt(0) every iter; with L3-resident
// panels (~500-900cy latency) and only ~3 blocks/CU that stall dominated
// (MfmaUtil 16%, VALUBusy 28%, HBM 12% -> stall-bound).
// ---------------------------------------------------------------------------

#define DIMC 768
#define HEADS 12
#define WIN 14
#define NTOK 196
#define NWIN 50
#define MROWS 9800
#define YROWS 8192
#define MLP_HID 3072

using bf16x8 = __attribute__((ext_vector_type(8))) short;
using f32x4  = __attribute__((ext_vector_type(4))) float;

__device__ __forceinline__ float bf2f(unsigned short u) {
    return __uint_as_float(((unsigned)u) << 16);
}
__device__ __forceinline__ unsigned short f2bf(float f) {
    unsigned u = __float_as_uint(f);
    unsigned r = (u + 0x7fffu + ((u >> 16) & 1u)) >> 16;   // round-nearest-even
    return (unsigned short)r;
}
__device__ __forceinline__ void gl2lds16(const unsigned short* g, unsigned short* l) {
    __builtin_amdgcn_global_load_lds(
        (const __attribute__((address_space(1))) void*)g,
        (__attribute__((address_space(3))) void*)l, 16, 0, 0);
}

// Branchless exact-enough gelu: 0.5*v*(1+erf(v/sqrt(2))).
// erf via Abramowitz-Stegun 7.1.26 (max err 1.5e-7 < bf16 quantum).
__device__ __forceinline__ float fast_gelu(float v) {
    float u = v * 0.70710678118654752f;
    float a = fabsf(u);
    float t = __builtin_amdgcn_rcpf(fmaf(0.3275911f, a, 1.0f));
    float p = t * fmaf(t, fmaf(t, fmaf(t, fmaf(t, 1.061405429f, -1.453152027f),
                       1.421413741f), -0.284496736f), 0.254829592f);
    float e = __expf(-u * u);
    float er = fmaf(-p, e, 1.0f);            // erf(|u|)
    er = copysignf(er, v);
    return 0.5f * v * (1.0f + er);
}

// ---------------- fused 4-way weight transpose: W (K x N, f32) -> Wt (N x K, bf16)
// block ranges: [0,432) qkv  [432,576) proj  [576,1152) fc1  [1152,1728) fc2
__global__ __launch_bounds__(256) void transpose_all(
        const float* __restrict__ Wq, unsigned short* __restrict__ Tq,
        const float* __restrict__ Wp, unsigned short* __restrict__ Tp,
        const float* __restrict__ W1, unsigned short* __restrict__ T1,
        const float* __restrict__ W2, unsigned short* __restrict__ T2) {
    int id = blockIdx.x;
    const float* W; unsigned short* Wt; int K, N, nbx, rel;
    if (id < 432)       { W = Wq; Wt = Tq; K = 768;  N = 2304; nbx = 36; rel = id; }
    else if (id < 576)  { W = Wp; Wt = Tp; K = 768;  N = 768;  nbx = 12; rel = id - 432; }
    else if (id < 1152) { W = W1; Wt = T1; K = 768;  N = 3072; nbx = 48; rel = id - 576; }
    else                { W = W2; Wt = T2; K = 3072; N = 768;  nbx = 12; rel = id - 1152; }
    int bx = rel % nbx, by = rel / nbx;
    __shared__ float t[64][65];
    int k0 = by << 6, n0 = bx << 6;
    int tn = threadIdx.x & 63;
    int tk = threadIdx.x >> 6;
    #pragma unroll
    for (int r = 0; r < 16; r++) {
        int k = tk + r * 4;
        t[k][tn] = W[(size_t)(k0 + k) * N + n0 + tn];
    }
    __syncthreads();
    #pragma unroll
    for (int r = 0; r < 16; r++) {
        int n = tk + r * 4;
        Wt[(size_t)(n0 + n) * K + k0 + tn] = f2bf(t[tn][n]);
    }
}

// ---------------- LN1 + window partition (zeros in padding) ----------------
__global__ __launch_bounds__(256) void ln1_win_kernel(
        const float* __restrict__ x, const float* __restrict__ g,
        const float* __restrict__ b, unsigned short* __restrict__ h1) {
    int tid = threadIdx.x;
    int row = blockIdx.x * 4 + (tid >> 6);
    int lane = tid & 63;
    if (row >= MROWS) return;
    int w = row / NTOK, t = row % NTOK;
    int bi = w / 25, wr = w % 25;
    int gy = (wr / 5) * WIN + t / WIN;
    int gx = (wr % 5) * WIN + t % WIN;
    unsigned short* out = h1 + (size_t)row * DIMC;
    if (gy >= 64 || gx >= 64) {           // reference pads AFTER LN -> zeros
        #pragma unroll
        for (int j = 0; j < 12; j++) out[lane + 64 * j] = 0;
        return;
    }
    const float* xr = x + ((size_t)((bi * 64 + gy) * 64 + gx)) * DIMC;
    float v[12], s = 0.f;
    #pragma unroll
    for (int j = 0; j < 12; j++) { v[j] = xr[lane + 64 * j]; s += v[j]; }
    #pragma unroll
    for (int o = 32; o > 0; o >>= 1) s += __shfl_xor(s, o);
    float mean = s * (1.f / 768.f);
    float q = 0.f;
    #pragma unroll
    for (int j = 0; j < 12; j++) { float d = v[j] - mean; q += d * d; }
    #pragma unroll
    for (int o = 32; o > 0; o >>= 1) q += __shfl_xor(q, o);
    float inv = rsqrtf(q * (1.f / 768.f) + 1e-6f);
    #pragma unroll
    for (int j = 0; j < 12; j++) {
        int c = lane + 64 * j;
        out[c] = f2bf((v[j] - mean) * inv * g[c] + b[c]);
    }
}

// ---------------- LN2 ----------------
__global__ __launch_bounds__(256) void ln2_kernel(
        const float* __restrict__ y, const float* __restrict__ g,
        const float* __restrict__ b, unsigned short* __restrict__ h2) {
    int tid = threadIdx.x;
    int row = blockIdx.x * 4 + (tid >> 6);
    int lane = tid & 63;
    const float* xr = y + (size_t)row * DIMC;
    float v[12], s = 0.f;
    #pragma unroll
    for (int j = 0; j < 12; j++) { v[j] = xr[lane + 64 * j]; s += v[j]; }
    #pragma unroll
    for (int o = 32; o > 0; o >>= 1) s += __shfl_xor(s, o);
    float mean = s * (1.f / 768.f);
    float q = 0.f;
    #pragma unroll
    for (int j = 0; j < 12; j++) { float d = v[j] - mean; q += d * d; }
    #pragma unroll
    for (int o = 32; o > 0; o >>= 1) q += __shfl_xor(q, o);
    float inv = rsqrtf(q * (1.f / 768.f) + 1e-6f);
    unsigned short* out = h2 + (size_t)row * DIMC;
    #pragma unroll
    for (int j = 0; j < 12; j++) {
        int c = lane + 64 * j;
        out[c] = f2bf((v[j] - mean) * inv * g[c] + b[c]);
    }
}

// ---------------- build A_aug (q | relh | relw | 0) and Vt per (win,head) ----
// rel dots via MFMA: dots[i][r] = q[i] . RT[r], RT = [relph(27) | relpw(27)].
// relh[i][c] = dots[i][13 + i/14 - c]; relw[i][c] = dots[i][27 + 13 + i%14 - c].
__global__ __launch_bounds__(256) void build_aug(
        const unsigned short* __restrict__ qkvb,
        const float* __restrict__ relph, const float* __restrict__ relpw,
        unsigned short* __restrict__ Aaug, unsigned short* __restrict__ Vt) {
    __shared__ unsigned short qs[208 * 72];   // pitch 72: b128-aligned, 2-way banks
    __shared__ unsigned short rt[64 * 72];
    int tid = threadIdx.x;
    int bh = blockIdx.x, w = bh / HEADS, head = bh % HEADS;
    int lane = tid & 63, wave = tid >> 6;
    int l15 = lane & 15, q4 = lane >> 4, q8 = q4 * 8;
    size_t base = (size_t)w * NTOK * 2304 + head * 64;
    unsigned short* ab = Aaug + (size_t)bh * 256 * 96;

    // stage q -> qs, copy to ab cols 0..63
    for (int e = tid; e < 196 * 8; e += 256) {
        int t = e >> 3, s8 = (e & 7) * 8;
        bf16x8 qv = *(const bf16x8*)&qkvb[base + (size_t)t * 2304 + s8];
        *(bf16x8*)&qs[t * 72 + s8] = qv;
        *(bf16x8*)&ab[t * 96 + s8] = qv;
    }
    for (int e = tid; e < 12 * 8; e += 256) {  // zero qs rows 196..207
        bf16x8 z = {};
        *(bf16x8*)&qs[(196 + (e >> 3)) * 72 + (e & 7) * 8] = z;
    }
    // stage RT tables (f32 -> bf16), rows 54..63 zero
    for (int e = tid; e < 64 * 8; e += 256) {
        int r = e >> 3, s8 = (e & 7) * 8;
        bf16x8 ov = {};
        if (r < 54) {
            const float* src = (r < 27 ? relph + (size_t)r * 64
                                       : relpw + (size_t)(r - 27) * 64) + s8;
            #pragma unroll
            for (int jj = 0; jj < 8; jj++) ov[jj] = (short)f2bf(src[jj]);
        }
        *(bf16x8*)&rt[r * 72 + s8] = ov;
    }
    // zero ab rows 196..255 (all 96 cols) and cols 92..95
    for (int e = tid; e < 60 * 12; e += 256) {
        bf16x8 z = {};
        *(bf16x8*)&ab[(size_t)(196 + e / 12) * 96 + (e % 12) * 8] = z;
    }
    for (int e = tid; e < 196; e += 256) {
        ab[e * 96 + 92] = 0; ab[e * 96 + 93] = 0;
        ab[e * 96 + 94] = 0; ab[e * 96 + 95] = 0;
    }
    __syncthreads();

    // rel MFMA + scatter into ab cols 64..91
    #pragma unroll
    for (int t = 0; t < 4; t++) {
        int it = wave * 4 + t;
        if (it >= 13) break;                      // wave-uniform
        bf16x8 a0 = *(bf16x8*)&qs[(it * 16 + l15) * 72 + q8];
        bf16x8 a1 = *(bf16x8*)&qs[(it * 16 + l15) * 72 + 32 + q8];
        #pragma unroll
        for (int rt4 = 0; rt4 < 4; rt4++) {
            bf16x8 b0 = *(bf16x8*)&rt[(rt4 * 16 + l15) * 72 + q8];
            bf16x8 b1 = *(bf16x8*)&rt[(rt4 * 16 + l15) * 72 + 32 + q8];
            f32x4 d4 = {};
            d4 = __builtin_amdgcn_mfma_f32_16x16x32_bf16(a0, b0, d4, 0, 0, 0);
            d4 = __builtin_amdgcn_mfma_f32_16x16x32_bf16(a1, b1, d4, 0, 0, 0);
            int rcol = rt4 * 16 + l15;
            #pragma unroll
            for (int r = 0; r < 4; r++) {
                int i = it * 16 + q4 * 4 + r;
                if (i < 196 && rcol < 54) {
                    if (rcol < 27) {
                        int c = 13 + i / 14 - rcol;
                        if (c >= 0 && c < 14) ab[i * 96 + 64 + c] = f2bf(d4[r]);
                    } else {
                        int c = 13 + i % 14 - (rcol - 27);
                        if (c >= 0 && c < 14) ab[i * 96 + 78 + c] = f2bf(d4[r]);
                    }
                }
            }
        }
    }

    // Vt[d][224]: vector read V, scalar global scatter (L2 write-combines)
    unsigned short* vtb = Vt + (size_t)bh * 64 * 224;
    for (int e = tid; e < 196 * 8; e += 256) {
        int j = e >> 3, dg = (e & 7) * 8;
        bf16x8 vv = *(const bf16x8*)&qkvb[base + 1536 + (size_t)j * 2304 + dg];
        #pragma unroll
        for (int k = 0; k < 8; k++)
            vtb[(size_t)(dg + k) * 224 + j] = (unsigned short)vv[k];
    }
    for (int e = tid; e < 64 * 28; e += 256)     // zero cols 196..223
        vtb[(size_t)(e / 28) * 224 + 196 + (e % 28)] = 0;
}

// ---------------- fused MFMA attention: one block per (window,head) --------
__global__ __launch_bounds__(256) void attn_mfma(
        const unsigned short* __restrict__ qkvb,
        const unsigned short* __restrict__ Aaug,
        const unsigned short* __restrict__ Vt,
        unsigned short* __restrict__ out) {
    __shared__ unsigned short Kls[208 * 96];   // K_aug: [k*0.125 | oh(j/14) | oh(j%14) | 0]
    __shared__ unsigned short Pls[4][64 * 40]; // per-wave P strip, pitch 40
    int tid = threadIdx.x;
    int bh = blockIdx.x, w = bh / HEADS, head = bh % HEADS;
    int wave = tid >> 6, lane = tid & 63;
    int l15 = lane & 15, q4 = lane >> 4, q8 = q4 * 8;
    size_t kbase = (size_t)w * NTOK * 2304 + head * 64 + 768;
    // stage K*0.125 (exact: pow2) rows 0..195
    for (int e = tid; e < 196 * 8; e += 256) {
        int t = e >> 3, s8 = (e & 7) * 8;
        bf16x8 kv = *(const bf16x8*)&qkvb[kbase + (size_t)t * 2304 + s8];
        bf16x8 ko;
        #pragma unroll
        for (int jj = 0; jj < 8; jj++)
            ko[jj] = (short)f2bf(bf2f((unsigned short)kv[jj]) * 0.125f);
        *(bf16x8*)&Kls[t * 96 + s8] = ko;
    }
    bf16x8 z8 = {};
    for (int e = tid; e < 208 * 4; e += 256)   // zero cols 64..95
        *(bf16x8*)&Kls[(e >> 2) * 96 + 64 + (e & 3) * 8] = z8;
    for (int e = tid; e < 12 * 8; e += 256)    // zero rows 196..207 cols 0..63
        *(bf16x8*)&Kls[(196 + (e >> 3)) * 96 + (e & 7) * 8] = z8;
    __syncthreads();                           // zeros before one-hots (same dwords)
    for (int e = tid; e < 196; e += 256) {
        Kls[e * 96 + 64 + e / WIN] = 0x3F80;   // bf16(1.0)
        Kls[e * 96 + 78 + e % WIN] = 0x3F80;
    }
    // A-frags from global (held in regs across all j-tiles)
    bf16x8 af[4][3];
    const unsigned short* abse = Aaug + (size_t)bh * 256 * 96;
    #pragma unroll
    for (int it = 0; it < 4; it++)
        #pragma unroll
        for (int c = 0; c < 3; c++)
            af[it][c] = *(const bf16x8*)&abse[(size_t)(wave * 64 + it * 16 + l15) * 96 + c * 32 + q8];
    __syncthreads();                           // K_aug complete

    const unsigned short* vtb = Vt + (size_t)bh * 64 * 224;
    f32x4 o[4][4] = {};
    float lacc[4][4] = {{0.f}};
    bf16x8 bv[4];
    #pragma unroll
    for (int dt = 0; dt < 4; dt++)
        bv[dt] = *(const bf16x8*)&vtb[(dt * 16 + l15) * 224 + q8];

    for (int jp = 0; jp < 7; jp++) {
        f32x4 s[4][2] = {};
        #pragma unroll
        for (int half = 0; half < 2; half++) {
            int jt = jp * 2 + half;
            if (jt < 13) {
                #pragma unroll
                for (int c = 0; c < 3; c++) {
                    bf16x8 bk = *(bf16x8*)&Kls[(jt * 16 + l15) * 96 + c * 32 + q8];
                    #pragma unroll
                    for (int it = 0; it < 4; it++)
                        s[it][half] = __builtin_amdgcn_mfma_f32_16x16x32_bf16(
                            af[it][c], bk, s[it][half], 0, 0, 0);
                }
            }
        }
        __syncthreads();   // WAR: previous PV reads of Pls complete
        #pragma unroll
        for (int half = 0; half < 2; half++) {
            int jt = jp * 2 + half;
            bool valid = (jt < 13) && (jt * 16 + l15) < 196;
            #pragma unroll
            for (int it = 0; it < 4; it++)
                #pragma unroll
                for (int r = 0; r < 4; r++) {
                    float p = valid ? __expf(s[it][half][r]) : 0.f;
                    unsigned short pb = f2bf(p);
                    lacc[it][r] += bf2f(pb);
                    Pls[wave][(it * 16 + q4 * 4 + r) * 40 + half * 16 + l15] = pb;
                }
        }
        __syncthreads();   // RAW: P visible
        bf16x8 ap[4];
        #pragma unroll
        for (int it = 0; it < 4; it++)
            ap[it] = *(bf16x8*)&Pls[wave][(it * 16 + l15) * 40 + q8];
        bf16x8 bvn[4];
        if (jp < 6) {
            #pragma unroll
            for (int dt = 0; dt < 4; dt++)
                bvn[dt] = *(const bf16x8*)&vtb[(dt * 16 + l15) * 224 + (jp + 1) * 32 + q8];
        }
        #pragma unroll
        for (int dt = 0; dt < 4; dt++)
            #pragma unroll
            for (int it = 0; it < 4; it++)
                o[it][dt] = __builtin_amdgcn_mfma_f32_16x16x32_bf16(
                    ap[it], bv[dt], o[it][dt], 0, 0, 0);
        if (jp < 6) {
            #pragma unroll
            for (int dt = 0; dt < 4; dt++) bv[dt] = bvn[dt];
        }
    }
    // row sums across the 16 j-lanes of each quad
    #pragma unroll
    for (int it = 0; it < 4; it++)
        #pragma unroll
        for (int r = 0; r < 4; r++) {
            float v = lacc[it][r];
            v += __shfl_xor(v, 1); v += __shfl_xor(v, 2);
            v += __shfl_xor(v, 4); v += __shfl_xor(v, 8);
            lacc[it][r] = 1.f / v;
        }
    // store O (win, token, head, d)
    #pragma unroll
    for (int it = 0; it < 4; it++) {
        int i0 = wave * 64 + it * 16 + q4 * 4;
        #pragma unroll
        for (int r = 0; r < 4; r++) {
            if (i0 + r < 196) {
                size_t rowb = (size_t)(w * NTOK + i0 + r) * DIMC + head * 64;
                #pragma unroll
                for (int dt = 0; dt < 4; dt++)
                    out[rowb + dt * 16 + l15] = f2bf(o[it][dt][r] * lacc[it][r]);
            }
        }
    }
}

// ---------------- MFMA GEMM (3-buffer 2-ahead pipeline + XCD swizzle + XOR
// LDS): C = A(MxK bf16) @ Bt(NxK bf16)^T + bias. BM=128, BN in {128,64}, BK=32.
// Counted vmcnt: barrier at iter t waits only for tile t's loads (vmcnt(LPT)
// leaves tile t+1 in flight); tile t+2 is issued into the buffer freed by
// iter t-1 (all waves' ds_reads of it completed before they crossed this
// barrier). Loads get ~2 compute phases to land instead of <1.
// EPI 0: bf16 store   EPI 1: fast exact-erf gelu -> bf16
// EPI 2: window-unpartition + x residual (f32)   EPI 3: + resid (f32)
template <int EPI, int BN>
__global__ __launch_bounds__(256) void mgemm(
        const unsigned short* __restrict__ A, const unsigned short* __restrict__ Bt,
        const float* __restrict__ bias, void* __restrict__ Cout,
        const float* __restrict__ resid, int M, int Nn, int K,
        int nbx, int nby) {
    const int NI = BN / 32;                 // per-wave n-frags
    constexpr int LPT = (BN == 128) ? 4 : 3;  // gl2lds16 per thread per tile
    __shared__ unsigned short As[3][128 * 32];
    __shared__ unsigned short Bs[3][BN * 32];
    int tid = threadIdx.x;
    int lane = tid & 63, wave = tid >> 6;
    int l15 = lane & 15, q4 = lane >> 4;
    int xq8 = (q4 ^ ((l15 >> 1) & 3)) * 8;  // swizzled frag segment (shorts)
    // ---- XCD swizzle ----
    int id = blockIdx.x;
    int per = nbx * 8;
    int s = id / per;
    int rem = id - s * per;
    int rmax = nby - s * 8; if (rmax > 8) rmax = 8;
    int bx = rem / rmax;
    int r_ = rem - bx * rmax;
    int by = s * 8 + r_;
    int m0 = by << 7, n0 = bx * BN;
    int wm = (wave >> 1) * 64, wn = (wave & 1) * (BN / 2);
    // staging: lane i -> row i/4, swizzled global seg; LDS dst = base + lane*16
    int srow0 = wave * 32 + (lane >> 2);
    int srow1 = srow0 + 16;
    int sseg = ((lane & 3) ^ ((lane >> 3) & 3)) * 8;   // shorts
    int rmA0 = m0 + srow0; if (rmA0 >= M) rmA0 = M - 1;   // clamp: rows>=M never stored
    int rmA1 = m0 + srow1; if (rmA1 >= M) rmA1 = M - 1;
    const unsigned short* gA0 = A + (size_t)rmA0 * K + sseg;
    const unsigned short* gA1 = A + (size_t)rmA1 * K + sseg;
    int browB = (BN == 128) ? srow0 : (wave * 16 + (lane >> 2));
    const unsigned short* gB0 = Bt + (size_t)(n0 + browB) * K + sseg;
    const unsigned short* gB1 = Bt + (size_t)(n0 + srow1) * K + sseg;  // BN=128 only
    int lofsA = wave * 1024 + lane * 8;
    int lofsB = ((BN == 128) ? wave * 1024 : wave * 512) + lane * 8;
    f32x4 acc[4][NI] = {};
    int nt = K >> 5;
    // prologue: stage tiles 0,1 into bufs 0,1 (issue order defines vmcnt FIFO)
    gl2lds16(gA0, &As[0][lofsA]);
    gl2lds16(gA1, &As[0][lofsA + 512]);
    gl2lds16(gB0, &Bs[0][lofsB]);
    if (BN == 128) gl2lds16(gB1, &Bs[0][lofsB + 512]);
    if (nt > 1) {
        gl2lds16(gA0 + 32, &As[1][lofsA]);
        gl2lds16(gA1 + 32, &As[1][lofsA + 512]);
        gl2lds16(gB0 + 32, &Bs[1][lofsB]);
        if (BN == 128) gl2lds16(gB1 + 32, &Bs[1][lofsB + 512]);
    }
    int cur = 0;
    for (int t = 0; t < nt; ++t) {
        if (t + 1 < nt) {
            // drain tile t only; tile t+1 (LPT loads) stays in flight
            asm volatile("s_waitcnt vmcnt(%0)" :: "i"(LPT) : "memory");
        } else {
            asm volatile("s_waitcnt vmcnt(0)" ::: "memory");
        }
        __builtin_amdgcn_s_barrier();
        if (t + 2 < nt) {                    // issue tile t+2 into freed buffer
            int b2 = cur + 2; if (b2 >= 3) b2 -= 3;
            int kn = (t + 2) << 5;
            gl2lds16(gA0 + kn, &As[b2][lofsA]);
            gl2lds16(gA1 + kn, &As[b2][lofsA + 512]);
            gl2lds16(gB0 + kn, &Bs[b2][lofsB]);
            if (BN == 128) gl2lds16(gB1 + kn, &Bs[b2][lofsB + 512]);
        }
        bf16x8 bfr[NI];
        #pragma unroll
        for (int ni = 0; ni < NI; ni++)
            bfr[ni] = *(bf16x8*)&Bs[cur][(wn + ni * 16 + l15) * 32 + xq8];
        #pragma unroll
        for (int mi = 0; mi < 4; mi++) {
            bf16x8 afr = *(bf16x8*)&As[cur][(wm + mi * 16 + l15) * 32 + xq8];
            #pragma unroll
            for (int ni = 0; ni < NI; ni++)
                acc[mi][ni] = __builtin_amdgcn_mfma_f32_16x16x32_bf16(
                    afr, bfr[ni], acc[mi][ni], 0, 0, 0);
        }
        cur = (cur == 2) ? 0 : cur + 1;
    }
    int q4r = (lane >> 4) * 4;
    #pragma unroll
    for (int mi = 0; mi < 4; mi++) {
        #pragma unroll
        for (int r = 0; r < 4; r++) {
            int row = m0 + wm + mi * 16 + q4r + r;
            if (row >= M) continue;
            if (EPI == 2) {
                int w = row / NTOK, t = row % NTOK;
                int bi = w / 25, wr = w % 25;
                int gy = (wr / 5) * WIN + t / WIN;
                int gx = (wr % 5) * WIN + t % WIN;
                if (gy >= 64 || gx >= 64) continue;
                size_t orow = ((size_t)((bi * 64 + gy) * 64 + gx)) * DIMC;
                #pragma unroll
                for (int ni = 0; ni < NI; ni++) {
                    int col = n0 + wn + ni * 16 + l15;
                    float v = acc[mi][ni][r] + bias[col];
                    ((float*)Cout)[orow + col] = resid[orow + col] + v;
                }
            } else {
                #pragma unroll
                for (int ni = 0; ni < NI; ni++) {
                    int col = n0 + wn + ni * 16 + l15;
                    float v = acc[mi][ni][r] + bias[col];
                    if (EPI == 0) {
                        ((unsigned short*)Cout)[(size_t)row * Nn + col] = f2bf(v);
                    } else if (EPI == 1) {
                        v = fast_gelu(v);
                        ((unsigned short*)Cout)[(size_t)row * Nn + col] = f2bf(v);
                    } else {
                        ((float*)Cout)[(size_t)row * Nn + col] =
                            resid[(size_t)row * Nn + col] + v;
                    }
                }
            }
        }
    }
}

// ---------------------------------------------------------------------------
extern "C" void kernel_launch(void* const* d_in, const int* in_sizes, int n_in,
                              void* d_out, int out_size, void* d_ws, size_t ws_size,
                              hipStream_t stream) {
    const float* x      = (const float*)d_in[0];
    const float* ln1_g  = (const float*)d_in[1];
    const float* ln1_b  = (const float*)d_in[2];
    const float* qkv_w  = (const float*)d_in[3];
    const float* qkv_b  = (const float*)d_in[4];
    const float* proj_w = (const float*)d_in[5];
    const float* proj_b = (const float*)d_in[6];
    const float* rel_h  = (const float*)d_in[7];
    const float* rel_w  = (const float*)d_in[8];
    const float* ln2_g  = (const float*)d_in[9];
    const float* ln2_b  = (const float*)d_in[10];
    const float* fc1_w  = (const float*)d_in[11];
    const float* fc1_b  = (const float*)d_in[12];
    const float* fc2_w  = (const float*)d_in[13];
    const float* fc2_b  = (const float*)d_in[14];
    float* out = (float*)d_out;
    char* ws = (char*)d_ws;

    // Workspace regions (max 121,061,376 B), liveness-checked (same as R3-R9):
    unsigned short* wt_qkv  = (unsigned short*)(ws);
    unsigned short* wt_proj = (unsigned short*)(ws + 3538944);
    unsigned short* wt_fc1  = (unsigned short*)(ws + 4718592);
    unsigned short* wt_fc2  = (unsigned short*)(ws + 9437184);
    unsigned short* qkvb    = (unsigned short*)(ws + 14155776);
    float*          yb      = (float*)        (ws + 14155776);
    unsigned short* h2      = (unsigned short*)(ws + 39321600);
    unsigned short* h1      = (unsigned short*)(ws + 59314176);
    unsigned short* attn_o  = h1;
    unsigned short* zb      = h1;
    unsigned short* Aaug    = (unsigned short*)(ws + 74366976);
    unsigned short* Vt      = (unsigned short*)(ws + 103858176);

    transpose_all<<<1728, 256, 0, stream>>>(
        qkv_w, wt_qkv, proj_w, wt_proj, fc1_w, wt_fc1, fc2_w, wt_fc2);

    ln1_win_kernel<<<(MROWS + 3) / 4, 256, 0, stream>>>(x, ln1_g, ln1_b, h1);

    mgemm<0, 128><<<18 * 77, 256, 0, stream>>>(
        h1, wt_qkv, qkv_b, qkvb, nullptr, MROWS, 2304, DIMC, 18, 77);

    build_aug<<<NWIN * HEADS, 256, 0, stream>>>(qkvb, rel_h, rel_w, Aaug, Vt);

    attn_mfma<<<NWIN * HEADS, 256, 0, stream>>>(qkvb, Aaug, Vt, attn_o);

    mgemm<2, 64><<<12 * 77, 256, 0, stream>>>(
        attn_o, wt_proj, proj_b, yb, x, MROWS, DIMC, DIMC, 12, 77);

    ln2_kernel<<<YROWS / 4, 256, 0, stream>>>(yb, ln2_g, ln2_b, h2);

    mgemm<1, 128><<<24 * 64, 256, 0, stream>>>(
        h2, wt_fc1, fc1_b, zb, nullptr, YROWS, MLP_HID, DIMC, 24, 64);

    mgemm<3, 64><<<12 * 64, 256, 0, stream>>>(
        zb, wt_fc2, fc2_b, out, yb, YROWS, DIMC, MLP_HID, 12, 64);
}